// Round 5
// baseline (200256.873 us; speedup 1.0000x reference)
//
#include <hip/hip_runtime.h>

#define NB    64
#define TT    2048
#define HH    256
#define DD    64
#define TGJ   224

// ---------------- workspace layout (float offsets) ----------------
#define O_C    0         // posterior cov 256x256
#define O_CA   65536     // C*A^T
#define O_AT   131072    // A^T
#define O_G    262144    // B*A (64x256)
#define O_BQ   278528    // B*Q (64x256)
#define O_SR   294912    // B*Q*B^T + R (64x64)
#define O_CBT  299008    // C*B^T (256x64)
#define O_CGT  315392    // C*G^T (256x64)
#define O_BP   331776    // B*P (64x256)
#define O_S    348160    // innovation cov (64x64)
#define O_T    352256    // S_prev*Yprev (64x64)
#define O_Y0   356352    // inverse tracker buf 0
#define O_Y1   360448    // inverse tracker buf 1
#define O_W    397312    // w = G*s (64)
#define O_SV   397376    // state (256)
#define O_IW   921920    // unsigned[65]: [0..63] arrive flags, [64] go

// ---------------- LDS layout (byte offsets into dynamic smem) ------
#define OF_AccT 0        // [256][32] xor-swz (k&7): A^T cols C0
#define OF_ArrT 32768    // [256][32] plain: A^T cols R0
#define OF_GrT  65536    // [256][8]: G rows r8 (transposed)
#define OF_GcT  73728    // [256][8]: G rows c8 (transposed)
#define OF_BcT  81920    // [256][8]: B rows c8 (transposed)
#define OF_SL   90112    // s_l[256]
#define OF_UL   91136    // u_l[32]
#define OF_INV  91264    // innov[64]
#define OF_PERM 91520    // perm[64] int
#define OF_FL   91776    // f_l[64]
#define OF_QT   92048    // [32][36]: Q tile
#define OF_BQS  96656    // [8][32]: BQ slice
#define OF_SRS  97680    // [64]: SR slice
#define U0      97936
#define OF_Crow (U0)            // [256][32] xor-swz (stage A)
#define OF_SrL  (U0 + 32768)    // [8][65] S_prev rows (stage A newton)
#define OF_YcL  (U0 + 34880)    // [64][8] Yprev col-block (stage A newton)
#define OF_CAs  (U0)            // [256][32] xor-swz (stage B)
#define OF_CGl  (U0 + 32768)    // [256][8] (stage B)
#define OF_YrL  (U0 + 40960)    // [8][65] Yprev rows (stage B newton)
#define OF_TcL  (U0 + 43072)    // [64][8] T col-block (stage B newton)
#define OF_Yl   (U0)            // [64][64] (stage C)
#define OF_CBl  (U0 + 16384)    // [32][65]
#define OF_Kl   (U0 + 24704)    // [32][65]
#define OF_BPl  (U0 + 33024)    // [64][32]
#define OF_GJM  (U0 + 16384)    // [64][130] (GJ only)
#define SMEM_BYTES (U0 + 49664)
static_assert(SMEM_BYTES <= 163840, "LDS overflow");

// ---- agent-scope relaxed data movement (per-instruction coherence;
//      keeps XCD L2s clean so the barrier fences find nothing to flush) ----
__device__ __forceinline__ float2 ldA2(const float* p) {
  unsigned long long u = __hip_atomic_load((const unsigned long long*)p,
                                           __ATOMIC_RELAXED, __HIP_MEMORY_SCOPE_AGENT);
  union { unsigned long long u; float2 f; } c; c.u = u; return c.f;
}
__device__ __forceinline__ void stA2(float* p, float x, float y) {
  union { float2 f; unsigned long long u; } c; c.f = make_float2(x, y);
  __hip_atomic_store((unsigned long long*)p, c.u,
                     __ATOMIC_RELAXED, __HIP_MEMORY_SCOPE_AGENT);
}
__device__ __forceinline__ float ldA1(const float* p) {
  unsigned u = __hip_atomic_load((const unsigned*)p,
                                 __ATOMIC_RELAXED, __HIP_MEMORY_SCOPE_AGENT);
  return __uint_as_float(u);
}
__device__ __forceinline__ void stA1(float* p, float v) {
  __hip_atomic_store((unsigned*)p, __float_as_uint(v),
                     __ATOMIC_RELAXED, __HIP_MEMORY_SCOPE_AGENT);
}

// ---------------- flag-based grid barrier (64 co-resident blocks) --
__device__ __forceinline__ void gbar(unsigned* iw, unsigned& g, int blk, int tid) {
  ++g;
  __threadfence();
  __syncthreads();
  if (blk == 0) {
    if (tid > 0 && tid < NB) {
      while (__hip_atomic_load(&iw[tid], __ATOMIC_ACQUIRE, __HIP_MEMORY_SCOPE_AGENT) < g)
        __builtin_amdgcn_s_sleep(1);
    }
    __syncthreads();
    if (tid == 0)
      __hip_atomic_store(&iw[64], g, __ATOMIC_RELEASE, __HIP_MEMORY_SCOPE_AGENT);
  } else {
    if (tid == 0) {
      __hip_atomic_store(&iw[blk], g, __ATOMIC_RELEASE, __HIP_MEMORY_SCOPE_AGENT);
      while (__hip_atomic_load(&iw[64], __ATOMIC_ACQUIRE, __HIP_MEMORY_SCOPE_AGENT) < g)
        __builtin_amdgcn_s_sleep(1);
    }
  }
  __syncthreads();
  __threadfence();
}

// ---------------- 64x64 GJ inverse, private per block --------------
// Reads S from global (agent loads); output to Yl (LDS).
__device__ void gj_inv(const float* __restrict__ Sg, float* __restrict__ Yl,
                       float* M_, int* perm, float* f_l, int tid) {
  const int LD = 130;
  for (int o = tid; o < 64 * 64; o += 256) {
    int r2 = o >> 6, c2 = o & 63;
    M_[r2 * LD + c2] = ldA1(Sg + o);
    M_[r2 * LD + 64 + c2] = (r2 == c2) ? 1.f : 0.f;
  }
  if (tid < 64) perm[tid] = tid;
  __syncthreads();
  for (int k = 0; k < 64; ++k) {
    if (tid < 64) {
      int myp = perm[tid];
      float v = (tid >= k) ? fabsf(M_[myp * LD + k]) : -1.f;
      int bi = tid;
#pragma unroll
      for (int off = 32; off; off >>= 1) {
        float ov = __shfl_xor(v, off, 64);
        int oi = __shfl_xor(bi, off, 64);
        if (ov > v || (ov == v && oi < bi)) { v = ov; bi = oi; }
      }
      int oldpk = perm[k];
      int pkv = perm[bi];
      int newp = (tid == k) ? pkv : ((tid == bi) ? oldpk : myp);
      perm[tid] = newp;
      float ipiv = 1.f / M_[pkv * LD + k];
      f_l[tid] = (tid == k) ? ipiv : M_[newp * LD + k] * ipiv;
    }
    __syncthreads();
    {
      int pk = perm[k];
      const float* prow = M_ + pk * LD;
      int r2 = tid >> 2;
      int jo = tid & 3;  // stride-4 column interleave: ~2-way banks (was 4-way)
      if (r2 != k) {
        int pr = perm[r2];
        float f = f_l[r2];
        float* rrow = M_ + pr * LD;
#pragma unroll
        for (int jj = 0; jj < 32; ++jj) {
          int j = jo + (jj << 2);
          if (j > k) rrow[j] -= f * prow[j];
        }
      }
    }
    __syncthreads();
  }
  for (int o = tid; o < 64 * 64; o += 256) {
    int r2 = o >> 6, c2 = o & 63;
    int pr = perm[r2];
    Yl[o] = M_[pr * LD + 64 + c2] / M_[pr * LD + r2];
  }
}

// ---------------- init kernels -------------------------------------
__global__ void k_init1(const float* __restrict__ A, const float* __restrict__ B,
                        const float* __restrict__ Q, const float* __restrict__ s0,
                        float* __restrict__ ws) {
  int blk = blockIdx.x, tid = threadIdx.x;
  for (int o = tid; o < 1024; o += 256) {
    int idx = blk * 1024 + o;
    int i = idx >> 8, k = idx & 255;
    ws[O_C + idx] = (i == k) ? 1.f : 0.f;
    ws[O_AT + k * 256 + i] = A[i * 256 + k];
  }
  {
    int idx = blk * 256 + tid;
    int i = idx >> 8, j = idx & 255;
    float ag = 0.f, aq = 0.f;
#pragma unroll 8
    for (int k = 0; k < 256; ++k) {
      float b = B[i * 256 + k];
      ag += b * A[k * 256 + j];
      aq += b * Q[k * 256 + j];
    }
    ws[O_G + idx] = ag;
    ws[O_BQ + idx] = aq;
  }
  if (blk == 0) {
    ws[O_SV + tid] = s0[tid];
    if (tid < 65) ((unsigned*)(ws + O_IW))[tid] = 0u;
  }
}

__global__ void k_init2(const float* __restrict__ B, const float* __restrict__ R,
                        float* __restrict__ ws) {
  int idx = blockIdx.x * 64 + threadIdx.x;
  int i = idx >> 6, j = idx & 63;
  float a = R[i * 64 + j];
#pragma unroll 8
  for (int k = 0; k < 256; ++k) a += ws[O_BQ + i * 256 + k] * B[j * 256 + k];
  ws[O_SR + idx] = a;
}

// ---------------- phase A: full 2048-step recursion, 64 blocks -----
__global__ __launch_bounds__(256, 1) void k_phaseA(
    const float* __restrict__ A, const float* __restrict__ B,
    const float* __restrict__ Q, const float* __restrict__ R,
    const float* __restrict__ X, float* __restrict__ out,
    float* __restrict__ ws) {
  extern __shared__ __align__(16) char smem[];
  const int tid = threadIdx.x;
  const int blk = blockIdx.x;
  const int rt = blk >> 3, ct = blk & 7;
  const int R0 = rt * 32, C0 = ct * 32, r8 = rt * 8, c8 = ct * 8;
  const bool diag = (rt == ct);

  float* AccT = (float*)(smem + OF_AccT);
  float* ArrT = (float*)(smem + OF_ArrT);
  float* GrT  = (float*)(smem + OF_GrT);
  float* GcT  = (float*)(smem + OF_GcT);
  float* BcT  = (float*)(smem + OF_BcT);
  float* s_l  = (float*)(smem + OF_SL);
  float* u_l  = (float*)(smem + OF_UL);
  float* inv_l= (float*)(smem + OF_INV);
  int*   perm = (int*)  (smem + OF_PERM);
  float* f_l  = (float*)(smem + OF_FL);
  float* Qt   = (float*)(smem + OF_QT);
  float* BQs  = (float*)(smem + OF_BQS);
  float* SRs  = (float*)(smem + OF_SRS);
  float* CrowT= (float*)(smem + OF_Crow);
  float* SrL  = (float*)(smem + OF_SrL);
  float* YcL  = (float*)(smem + OF_YcL);
  float* CAs  = (float*)(smem + OF_CAs);
  float* CGl  = (float*)(smem + OF_CGl);
  float* YrL  = (float*)(smem + OF_YrL);
  float* TcL  = (float*)(smem + OF_TcL);
  float* Yl   = (float*)(smem + OF_Yl);
  float* CBl  = (float*)(smem + OF_CBl);
  float* Kl   = (float*)(smem + OF_Kl);
  float* BPl  = (float*)(smem + OF_BPl);
  float* gjm  = (float*)(smem + OF_GJM);

  unsigned* iw = (unsigned*)(ws + O_IW);

  // ---- static staging (once; private read-only data, normal loads) ----
  {
    const float4* AT4 = (const float4*)(ws + O_AT);
    for (int q = tid; q < 2048; q += 256) {
      int k = q >> 3, c4 = q & 7;
      float4 v = AT4[k * 64 + (C0 >> 2) + c4];
      *(float4*)(AccT + k * 32 + ((c4 ^ (k & 7)) << 2)) = v;
      float4 w2 = AT4[k * 64 + (R0 >> 2) + c4];
      *(float4*)(ArrT + k * 32 + (c4 << 2)) = w2;
    }
    const float4* G4 = (const float4*)(ws + O_G);
    const float4* B4 = (const float4*)B;
    for (int q = tid; q < 512; q += 256) {
      int i = q & 7, c4 = q >> 3;
      float4 vg = G4[(r8 + i) * 64 + c4];
      GrT[(c4 * 4 + 0) * 8 + i] = vg.x; GrT[(c4 * 4 + 1) * 8 + i] = vg.y;
      GrT[(c4 * 4 + 2) * 8 + i] = vg.z; GrT[(c4 * 4 + 3) * 8 + i] = vg.w;
      float4 vc = G4[(c8 + i) * 64 + c4];
      GcT[(c4 * 4 + 0) * 8 + i] = vc.x; GcT[(c4 * 4 + 1) * 8 + i] = vc.y;
      GcT[(c4 * 4 + 2) * 8 + i] = vc.z; GcT[(c4 * 4 + 3) * 8 + i] = vc.w;
      float4 vb = B4[(c8 + i) * 64 + c4];
      BcT[(c4 * 4 + 0) * 8 + i] = vb.x; BcT[(c4 * 4 + 1) * 8 + i] = vb.y;
      BcT[(c4 * 4 + 2) * 8 + i] = vb.z; BcT[(c4 * 4 + 3) * 8 + i] = vb.w;
    }
    const float4* Q4 = (const float4*)Q;
    {
      int r = tid >> 3, c4 = tid & 7;
      *(float4*)(Qt + r * 36 + c4 * 4) = Q4[(R0 + r) * 64 + (C0 >> 2) + c4];
    }
    if (tid < 64) {
      int r = tid >> 3, c4 = tid & 7;
      *(float4*)(BQs + r * 32 + c4 * 4) = ((const float4*)(ws + O_BQ))[(r8 + r) * 64 + (C0 >> 2) + c4];
      SRs[tid] = ws[O_SR + (r8 + (tid >> 3)) * 64 + c8 + (tid & 7)];
    }
  }
  __syncthreads();

  unsigned g = 0;
  for (int t = 0; t < TT; ++t) {
    const int p = t & 1;
    const bool gjmode = (t < TGJ);
    const bool newton = !gjmode;
    const float* Yprev = ws + (p ? O_Y1 : O_Y0);
    float* Ynext = ws + (p ? O_Y0 : O_Y1);
    float p0, p1, p2, p3;

    // ======= stage A: CA, CBt, CGt, diag w, newton: T = S_prev*Yprev =======
    {
      const float* Cb = ws + O_C;
      for (int q = tid; q < 2048; q += 256) {
        int ri = q >> 6, c4 = q & 63;
        const float* src = Cb + (R0 + ri) * 256 + c4 * 4;
        float2 va = ldA2(src), vb = ldA2(src + 2);
        int s = c4 & 31, k0 = c4 * 4;
        CrowT[(k0 + 0) * 32 + (ri ^ s)] = va.x;
        CrowT[(k0 + 1) * 32 + (ri ^ s)] = va.y;
        CrowT[(k0 + 2) * 32 + (ri ^ s)] = vb.x;
        CrowT[(k0 + 3) * 32 + (ri ^ s)] = vb.y;
      }
      if (newton) {
        for (int q = tid; q < 512; q += 256) {
          int r = q >> 6, k = q & 63;
          SrL[r * 65 + k] = ldA1(ws + O_S + (r8 + r) * 64 + k);
        }
        for (int q = tid; q < 512; q += 256) {
          int k = q >> 3, j = q & 7;
          YcL[k * 8 + j] = ldA1(Yprev + k * 64 + c8 + j);
        }
      }
      if (diag && tid < 64) {
        float2 sv = ldA2(ws + O_SV + tid * 4);
        float2 sw = ldA2(ws + O_SV + tid * 4 + 2);
        s_l[tid * 4 + 0] = sv.x; s_l[tid * 4 + 1] = sv.y;
        s_l[tid * 4 + 2] = sw.x; s_l[tid * 4 + 3] = sw.y;
      }
    }
    __syncthreads();
    {
      const int i = tid >> 3, jq = tid & 7, j0 = jq * 4;
      float ca0 = 0, ca1 = 0, ca2 = 0, ca3 = 0, cb = 0, cg = 0;
#pragma unroll 8
      for (int k = 0; k < 256; ++k) {
        float cv = CrowT[k * 32 + (i ^ ((k >> 2) & 31))];
        float4 av = *(const float4*)(AccT + k * 32 + ((jq ^ (k & 7)) << 2));
        ca0 += cv * av.x; ca1 += cv * av.y; ca2 += cv * av.z; ca3 += cv * av.w;
        cb += cv * BcT[k * 8 + jq];
        cg += cv * GcT[k * 8 + jq];
      }
      float* cap = ws + O_CA + (R0 + i) * 256 + C0 + j0;
      stA2(cap, ca0, ca1); stA2(cap + 2, ca2, ca3);
      stA1(ws + O_CBT + (R0 + i) * 64 + c8 + jq, cb);
      stA1(ws + O_CGT + (R0 + i) * 64 + c8 + jq, cg);
      if (newton && tid < 64) {  // T tile = S_prev * Yprev (8x8)
        int ti = tid >> 3, tj = tid & 7;
        float a = 0.f;
#pragma unroll 8
        for (int k = 0; k < 64; ++k) a += SrL[ti * 65 + k] * YcL[k * 8 + tj];
        stA1(ws + O_T + (r8 + ti) * 64 + c8 + tj, a);
      }
      if (diag) {
        if (tid < 32) {
          float a = 0;
#pragma unroll 8
          for (int k = 0; k < 256; ++k) a += ArrT[k * 32 + tid] * s_l[k];
          u_l[tid] = a;
        } else if (tid < 40) {
          int j = tid - 32;
          float a = 0;
#pragma unroll 8
          for (int k = 0; k < 256; ++k) a += GcT[k * 8 + j] * s_l[k];
          stA1(ws + O_W + c8 + j, a);
        }
      }
    }
    gbar(iw, g, blk, tid);

    // ======= stage B: P (regs), BP, S, newton: Ynew = 2Yp - Yp*T =======
    {
      for (int q = tid; q < 2048; q += 256) {
        int k = q >> 3, c4 = q & 7;
        const float* src = ws + O_CA + k * 256 + C0 + c4 * 4;
        float2 va = ldA2(src), vb = ldA2(src + 2);
        *(float4*)(CAs + k * 32 + ((c4 ^ (k & 7)) << 2)) = make_float4(va.x, va.y, vb.x, vb.y);
      }
      for (int q = tid; q < 512; q += 256) {
        int k = q >> 1, h = q & 1;
        const float* src = ws + O_CGT + k * 64 + c8 + h * 4;
        float2 va = ldA2(src), vb = ldA2(src + 2);
        *(float4*)(CGl + k * 8 + h * 4) = make_float4(va.x, va.y, vb.x, vb.y);
      }
      if (newton) {
        for (int q = tid; q < 512; q += 256) {
          int r = q >> 6, k = q & 63;
          YrL[r * 65 + k] = ldA1(Yprev + (r8 + r) * 64 + k);
        }
        for (int q = tid; q < 512; q += 256) {
          int k = q >> 3, j = q & 7;
          TcL[k * 8 + j] = ldA1(ws + O_T + k * 64 + c8 + j);
        }
      }
    }
    __syncthreads();
    {
      const int i = tid >> 3, jq = tid & 7, j0 = jq * 4;
      float pp0 = 0, pp1 = 0, pp2 = 0, pp3 = 0;
#pragma unroll 8
      for (int k = 0; k < 256; ++k) {
        float av = ArrT[k * 32 + i];
        float4 cv = *(const float4*)(CAs + k * 32 + ((jq ^ (k & 7)) << 2));
        pp0 += av * cv.x; pp1 += av * cv.y; pp2 += av * cv.z; pp3 += av * cv.w;
      }
      float4 qv = *(const float4*)(Qt + i * 36 + j0);
      p0 = pp0 + qv.x; p1 = pp1 + qv.y; p2 = pp2 + qv.z; p3 = pp3 + qv.w;
      const int ib = tid >> 5, jb = tid & 31;
      float bp = BQs[ib * 32 + jb];
#pragma unroll 8
      for (int k = 0; k < 256; ++k)
        bp += GrT[k * 8 + ib] * CAs[k * 32 + (((jb >> 2) ^ (k & 7)) << 2) + (jb & 3)];
      stA1(ws + O_BP + (r8 + ib) * 256 + C0 + jb, bp);
      if (tid < 64) {
        int si = tid >> 3, sj = tid & 7;
        float s = SRs[si * 8 + sj];
#pragma unroll 8
        for (int k = 0; k < 256; ++k) s += GrT[k * 8 + si] * CGl[k * 8 + sj];
        stA1(ws + O_S + (r8 + si) * 64 + c8 + sj, s);
      }
      if (newton && tid < 64) {  // Ynew tile = 2Yp - Yp*T (8x8)
        int yi = tid >> 3, yj = tid & 7;
        float a = 2.f * YrL[yi * 65 + c8 + yj];
#pragma unroll 8
        for (int k = 0; k < 64; ++k) a -= YrL[yi * 65 + k] * TcL[k * 8 + yj];
        stA1(Ynext + (r8 + yi) * 64 + c8 + yj, a);
      }
    }
    gbar(iw, g, blk, tid);

    // ======= stage C: inverse ready -> K, C' = P - K*BP, state =======
    if (gjmode) {
      gj_inv(ws + O_S, Yl, gjm, perm, f_l, tid);
      __syncthreads();
      if (blk == 0)
        for (int q = tid; q < 2048; q += 256)
          stA2(Ynext + q * 2, Yl[q * 2], Yl[q * 2 + 1]);
    } else {
      for (int q = tid; q < 1024; q += 256) {
        float2 va = ldA2(Ynext + q * 4), vb = ldA2(Ynext + q * 4 + 2);
        *(float4*)(Yl + q * 4) = make_float4(va.x, va.y, vb.x, vb.y);
      }
    }
    {
      for (int q = tid; q < 512; q += 256) {
        int ri = q >> 4, c4 = q & 15;
        const float* src = ws + O_CBT + (R0 + ri) * 64 + c4 * 4;
        float2 va = ldA2(src), vb = ldA2(src + 2);
        CBl[ri * 65 + c4 * 4 + 0] = va.x; CBl[ri * 65 + c4 * 4 + 1] = va.y;
        CBl[ri * 65 + c4 * 4 + 2] = vb.x; CBl[ri * 65 + c4 * 4 + 3] = vb.y;
      }
      for (int q = tid; q < 512; q += 256) {
        int m = q >> 3, c4 = q & 7;
        const float* src = ws + O_BP + m * 256 + C0 + c4 * 4;
        float2 va = ldA2(src), vb = ldA2(src + 2);
        *(float4*)(BPl + m * 32 + c4 * 4) = make_float4(va.x, va.y, vb.x, vb.y);
      }
      if (diag && tid < 64) inv_l[tid] = X[t * 64 + tid] - ldA1(ws + O_W + tid);
    }
    __syncthreads();
    {  // K rows R0..R0+31: K = CBt * Y
      const int i = tid >> 3, m0 = (tid & 7) * 8;
      float ka[8] = {0, 0, 0, 0, 0, 0, 0, 0};
#pragma unroll 4
      for (int k = 0; k < 64; ++k) {
        float cbv = CBl[i * 65 + k];
        float4 ya = *(const float4*)(Yl + k * 64 + m0);
        float4 yb = *(const float4*)(Yl + k * 64 + m0 + 4);
        ka[0] += cbv * ya.x; ka[1] += cbv * ya.y; ka[2] += cbv * ya.z; ka[3] += cbv * ya.w;
        ka[4] += cbv * yb.x; ka[5] += cbv * yb.y; ka[6] += cbv * yb.z; ka[7] += cbv * yb.w;
      }
#pragma unroll
      for (int mm = 0; mm < 8; ++mm) Kl[i * 65 + m0 + mm] = ka[mm];
    }
    __syncthreads();
    {  // C' tile
      const int i = tid >> 3, jq = tid & 7, j0 = jq * 4;
      float c0 = p0, c1 = p1, c2 = p2, c3 = p3;
#pragma unroll 4
      for (int m = 0; m < 64; ++m) {
        float kv = Kl[i * 65 + m];
        float4 bp = *(const float4*)(BPl + m * 32 + j0);
        c0 -= kv * bp.x; c1 -= kv * bp.y; c2 -= kv * bp.z; c3 -= kv * bp.w;
      }
      float* cp = ws + O_C + (R0 + i) * 256 + C0 + j0;
      stA2(cp, c0, c1); stA2(cp + 2, c2, c3);
    }
    if (diag && tid < 32) {  // state update + output
      float sn = u_l[tid];
#pragma unroll 8
      for (int j = 0; j < 64; ++j) sn += Kl[tid * 65 + j] * inv_l[j];
      out[t * 256 + R0 + tid] = sn;
      stA1(ws + O_SV + R0 + tid, sn);
    }
    gbar(iw, g, blk, tid);
  }
}

// ---------------- host entry ---------------------------------------
extern "C" void kernel_launch(void* const* d_in, const int* in_sizes, int n_in,
                              void* d_out, int out_size, void* d_ws, size_t ws_size,
                              hipStream_t stream) {
  const float* X  = (const float*)d_in[0];
  // d_in[1]=timeline, d_in[2]=mask: unused by reference math
  const float* A  = (const float*)d_in[3];
  const float* B  = (const float*)d_in[4];
  const float* Q  = (const float*)d_in[5];
  const float* R  = (const float*)d_in[6];
  const float* s0 = (const float*)d_in[7];
  float* out = (float*)d_out;
  float* ws  = (float*)d_ws;

  (void)hipFuncSetAttribute((const void*)k_phaseA,
                            hipFuncAttributeMaxDynamicSharedMemorySize, SMEM_BYTES);

  k_init1<<<64, 256, 0, stream>>>(A, B, Q, s0, ws);
  k_init2<<<64, 64, 0, stream>>>(B, R, ws);
  k_phaseA<<<64, 256, SMEM_BYTES, stream>>>(A, B, Q, R, X, out, ws);
}